// Round 7
// baseline (538.507 us; speedup 1.0000x reference)
//
#include <hip/hip_runtime.h>
#include <hip/hip_fp16.h>

#define FIN 16
#define HH 64
#define STILE 256

static constexpr float LN_EPS = 1e-5f;

__device__ __forceinline__ float laneval(float v, int l) {
  return __uint_as_float(__builtin_amdgcn_readlane(__float_as_uint(v), l));
}
__device__ __forceinline__ int rfl(int v) { return __builtin_amdgcn_readfirstlane(v); }
__device__ __forceinline__ float rflf(float v) {
  return __uint_as_float(__builtin_amdgcn_readfirstlane(__float_as_uint(v)));
}

// ---- edge dtype detection: int64 edge_index has all-zero high words ----
__global__ void k_detect(const unsigned int* ei, int E, int* flag) {
  int lane = threadIdx.x & 63;
  int n = (E < 64) ? E : 64;
  unsigned int hi = (lane < n) ? ei[2 * lane + 1] : 0u;
  unsigned long long nz = __ballot(hi != 0u);
  if (lane == 0) *flag = (nz == 0ull) ? 1 : 0;
}

// ---- in-degree histogram over dst ----
// ONE EDGE PER THREAD: round-6 k_fill was atomic-latency-bound (VALUBusy
// 0.26%) because 3 dependent atomic round-trips per thread serialized.
// Full-width grid makes every atomic independent -> TLP hides latency.
__global__ void k_hist(const void* ei, int E, const int* __restrict__ flag,
                       int* __restrict__ deg) {
  const int is64 = *flag;
  int e = blockIdx.x * blockDim.x + threadIdx.x;
  if (e >= E) return;
  int d = is64 ? (int)((const long long*)ei)[E + e] : ((const int*)ei)[E + e];
  atomicAdd(&deg[d], 1);
}

// ---- scan level 1: per-tile sums ----
__global__ void k_scan1(const int* __restrict__ deg, int N, int* __restrict__ partials) {
  __shared__ int sm[STILE];
  int t = threadIdx.x, b = blockIdx.x;
  int i = b * STILE + t;
  int v = (i < N) ? deg[i] : 0;
  sm[t] = v;
  __syncthreads();
  for (int off = STILE / 2; off > 0; off >>= 1) {
    if (t < off) sm[t] += sm[t + off];
    __syncthreads();
  }
  if (t == 0) partials[b] = sm[0];
}

// ---- scan level 2: single-block scan of tile sums -> exclusive tile bases ----
__global__ void k_scan2(int* partials, int numTiles) {
  __shared__ int sm[1024];
  int t = threadIdx.x;
  int v = (t < numTiles) ? partials[t] : 0;
  sm[t] = v;
  __syncthreads();
  for (int off = 1; off < 1024; off <<= 1) {
    int x = (t >= off) ? sm[t - off] : 0;
    __syncthreads();
    sm[t] += x;
    __syncthreads();
  }
  if (t < numTiles) partials[t] = sm[t] - v;  // exclusive base
}

// ---- scan level 3: per-element offsets, cursor init, inv_deg ----
// NOTE: cursor may alias deg — each thread reads deg[i] before writing cursor[i].
__global__ void k_scan3(const int* __restrict__ deg, int N,
                        const int* __restrict__ partials,
                        int* __restrict__ offsets, int* cursor,
                        float* __restrict__ inv_deg) {
  __shared__ int sm[STILE];
  int t = threadIdx.x, b = blockIdx.x;
  int i = b * STILE + t;
  int v = (i < N) ? deg[i] : 0;
  sm[t] = v;
  __syncthreads();
  for (int off = 1; off < STILE; off <<= 1) {
    int x = (t >= off) ? sm[t - off] : 0;
    __syncthreads();
    sm[t] += x;
    __syncthreads();
  }
  int excl = sm[t] - v + partials[b];
  if (i < N) {
    offsets[i] = excl;
    inv_deg[i] = (v > 0) ? (1.0f / (float)v) : 0.0f;
    if (i == N - 1) offsets[N] = excl + v;
    cursor[i] = excl;  // after deg[i] read (aliasing-safe)
  }
}

// ---- CSR fill: csr[pos] = src, grouped by dst ----
// ONE EDGE PER THREAD (see k_hist). csr store nontemporal: no reuse,
// keep it out of L2.
__global__ void k_fill(const void* ei, int E, const int* __restrict__ flag,
                       int* __restrict__ cursor, int* __restrict__ csr) {
  const int is64 = *flag;
  int e = blockIdx.x * blockDim.x + threadIdx.x;
  if (e >= E) return;
  int s, d;
  if (is64) {
    const long long* p = (const long long*)ei;
    s = (int)p[e];
    d = (int)p[E + e];
  } else {
    const int* p = (const int*)ei;
    s = p[e];
    d = p[E + e];
  }
  int pos = atomicAdd(&cursor[d], 1);
  __builtin_nontemporal_store(s, &csr[pos]);
}

// ---- input projection: h = relu(x @ Wp^T + bp), one wave per node ----
__global__ __launch_bounds__(256) void k_inproj(const float* __restrict__ x,
                                                const float* __restrict__ Wp,
                                                const float* __restrict__ bp,
                                                float* __restrict__ h,
                                                __half* __restrict__ h16, int N) {
  int lane = threadIdx.x & 63;
  int wid = (blockIdx.x * blockDim.x + threadIdx.x) >> 6;
  int nwaves = (gridDim.x * blockDim.x) >> 6;
  float w[FIN];
#pragma unroll
  for (int k = 0; k < FIN; ++k) w[k] = Wp[lane * FIN + k];
  float b = bp[lane];
  for (int n = wid; n < N; n += nwaves) {
    const float4* xr = (const float4*)(x + (size_t)n * FIN);
    float a0 = b, a1 = 0.f;
#pragma unroll
    for (int q = 0; q < FIN / 4; ++q) {
      float4 xv = xr[q];
      a0 = fmaf(xv.x, w[4 * q + 0], a0);
      a1 = fmaf(xv.y, w[4 * q + 1], a1);
      a0 = fmaf(xv.z, w[4 * q + 2], a0);
      a1 = fmaf(xv.w, w[4 * q + 3], a1);
    }
    float r = fmaxf(a0 + a1, 0.0f);
    h[(size_t)n * HH + lane] = r;
    h16[(size_t)n * HH + lane] = __float2half(r);
  }
}

// ---- neighbor-mean gather ONLY: agg16[n] = mean of h16 rows ----
// Tiny kernel (low VGPR -> 8 waves/SIMD) so many random loads stay in
// flight; monolithic round-3 kernel was gather-latency-bound at 20% occ.
__global__ __launch_bounds__(256, 8) void k_gather(
    const __half* __restrict__ h16_in, const int* __restrict__ offsets,
    const int* __restrict__ csr, const float* __restrict__ inv_deg,
    __half* __restrict__ agg16, int N) {
  int lane = threadIdx.x & 63;
  int wid = (blockIdx.x * blockDim.x + threadIdx.x) >> 6;
  int nwaves = (gridDim.x * blockDim.x) >> 6;
  for (int n = wid; n < N; n += nwaves) {
    int p0 = rfl(offsets[n]);
    int p1 = rfl(offsets[n + 1]);
    float idg = rflf(inv_deg[n]);
    float a0 = 0.f, a1 = 0.f, a2 = 0.f, a3 = 0.f;
    int p = p0;
    for (; p + 16 <= p1; p += 16) {
      float v[16];
#pragma unroll
      for (int i = 0; i < 16; ++i) {
        int s = rfl(csr[p + i]);
        v[i] = __half2float(h16_in[(size_t)s * HH + lane]);
      }
      a0 += (v[0] + v[1]) + (v[2] + v[3]);
      a1 += (v[4] + v[5]) + (v[6] + v[7]);
      a2 += (v[8] + v[9]) + (v[10] + v[11]);
      a3 += (v[12] + v[13]) + (v[14] + v[15]);
    }
    for (; p + 4 <= p1; p += 4) {
      int s0 = rfl(csr[p + 0]), s1 = rfl(csr[p + 1]);
      int s2 = rfl(csr[p + 2]), s3 = rfl(csr[p + 3]);
      float v0 = __half2float(h16_in[(size_t)s0 * HH + lane]);
      float v1 = __half2float(h16_in[(size_t)s1 * HH + lane]);
      float v2 = __half2float(h16_in[(size_t)s2 * HH + lane]);
      float v3 = __half2float(h16_in[(size_t)s3 * HH + lane]);
      a0 += (v0 + v1) + (v2 + v3);
    }
    for (; p < p1; ++p) {
      int s = rfl(csr[p]);
      a0 += __half2float(h16_in[(size_t)s * HH + lane]);
    }
    agg16[(size_t)n * HH + lane] = __float2half(((a0 + a1) + (a2 + a3)) * idg);
  }
}

// ---- GEMV x2 + LayerNorm + relu + residual, 2 nodes per wave ----
__global__ __launch_bounds__(256) void k_gemv(
    const float* __restrict__ h_in, const __half* __restrict__ agg16,
    float* __restrict__ h_out, __half* __restrict__ h16_out,
    const float* __restrict__ Wl, const float* __restrict__ bl,
    const float* __restrict__ Wr, const float* __restrict__ gamma,
    const float* __restrict__ beta, int N) {
  int lane = threadIdx.x & 63;
  int wid = (blockIdx.x * blockDim.x + threadIdx.x) >> 6;
  int nwaves = (gridDim.x * blockDim.x) >> 6;
  float blv = bl[lane], g = gamma[lane], be = beta[lane];
  const float4* wlr = (const float4*)(Wl + lane * HH);
  const float4* wrr = (const float4*)(Wr + lane * HH);

  for (int n = 2 * wid; n < N; n += 2 * nwaves) {
    int m2 = (n + 1 < N) ? (n + 1) : n;  // tail duplicates own node (benign)
    float hnA = h_in[(size_t)n * HH + lane];
    float hnB = h_in[(size_t)m2 * HH + lane];
    float acA = __half2float(agg16[(size_t)n * HH + lane]);
    float acB = __half2float(agg16[(size_t)m2 * HH + lane]);

    float olA = blv, orA = 0.f, olB = blv, orB = 0.f;
#pragma unroll
    for (int q = 0; q < HH / 4; ++q) {
      float4 wl4 = wlr[q];
      float4 wr4 = wrr[q];
      olA = fmaf(laneval(acA, 4 * q + 0), wl4.x, olA);
      olB = fmaf(laneval(acB, 4 * q + 0), wl4.x, olB);
      orA = fmaf(laneval(hnA, 4 * q + 0), wr4.x, orA);
      orB = fmaf(laneval(hnB, 4 * q + 0), wr4.x, orB);
      olA = fmaf(laneval(acA, 4 * q + 1), wl4.y, olA);
      olB = fmaf(laneval(acB, 4 * q + 1), wl4.y, olB);
      orA = fmaf(laneval(hnA, 4 * q + 1), wr4.y, orA);
      orB = fmaf(laneval(hnB, 4 * q + 1), wr4.y, orB);
      olA = fmaf(laneval(acA, 4 * q + 2), wl4.z, olA);
      olB = fmaf(laneval(acB, 4 * q + 2), wl4.z, olB);
      orA = fmaf(laneval(hnA, 4 * q + 2), wr4.z, orA);
      orB = fmaf(laneval(hnB, 4 * q + 2), wr4.z, orB);
      olA = fmaf(laneval(acA, 4 * q + 3), wl4.w, olA);
      olB = fmaf(laneval(acB, 4 * q + 3), wl4.w, olB);
      orA = fmaf(laneval(hnA, 4 * q + 3), wr4.w, orA);
      orB = fmaf(laneval(hnB, 4 * q + 3), wr4.w, orB);
    }

#pragma unroll
    for (int b = 0; b < 2; ++b) {
      float out = (b == 0) ? (olA + orA) : (olB + orB);
      float hn = (b == 0) ? hnA : hnB;
      int m = (b == 0) ? n : m2;
      float s = out;
#pragma unroll
      for (int msk = 1; msk < 64; msk <<= 1) s += __shfl_xor(s, msk);
      float mu = s * (1.0f / 64.0f);
      float d = out - mu;
      float vs = d * d;
#pragma unroll
      for (int msk = 1; msk < 64; msk <<= 1) vs += __shfl_xor(vs, msk);
      float var = vs * (1.0f / 64.0f);
      float val = fmaf(d * rsqrtf(var + LN_EPS), g, be);
      float res = fmaxf(val, 0.0f) + hn;
      h_out[(size_t)m * HH + lane] = res;
      h16_out[(size_t)m * HH + lane] = __float2half(res);
    }
  }
}

// ---- MLP head: y = relu(h@W1^T + b1) @ W2^T + b2 ; 2 nodes per wave ----
__global__ __launch_bounds__(256) void k_mlp(const float* __restrict__ h,
                                             const float* __restrict__ W1,
                                             const float* __restrict__ b1,
                                             const float* __restrict__ W2,
                                             const float* __restrict__ b2,
                                             float* __restrict__ y, int N) {
  int lane = threadIdx.x & 63;
  int half = lane >> 5;
  int j = lane & 31;
  int wid = (blockIdx.x * blockDim.x + threadIdx.x) >> 6;
  int nwaves = (gridDim.x * blockDim.x) >> 6;

  float w1[HH];
#pragma unroll
  for (int k = 0; k < HH; ++k) w1[k] = W1[j * HH + k];
  float b1v = b1[j], w2v = W2[j], b2v = b2[0];

  for (int base = wid * 2; base < N; base += nwaves * 2) {
    int n = base + half;
    float t0 = b1v, t1 = 0.0f;
    if (n < N) {
      const float4* hr = (const float4*)(h + (size_t)n * HH);
#pragma unroll
      for (int q = 0; q < HH / 4; ++q) {
        float4 hv = hr[q];
        t0 = fmaf(hv.x, w1[4 * q + 0], t0);
        t1 = fmaf(hv.y, w1[4 * q + 1], t1);
        t0 = fmaf(hv.z, w1[4 * q + 2], t0);
        t1 = fmaf(hv.w, w1[4 * q + 3], t1);
      }
    }
    float t = fmaxf(t0 + t1, 0.0f) * w2v;
#pragma unroll
    for (int m = 1; m < 32; m <<= 1) t += __shfl_xor(t, m);  // stays in half
    if (j == 0 && n < N) y[n] = t + b2v;
  }
}

extern "C" void kernel_launch(void* const* d_in, const int* in_sizes, int n_in,
                              void* d_out, int out_size, void* d_ws, size_t ws_size,
                              hipStream_t stream) {
  const float* x = (const float*)d_in[0];
  const void* ei = d_in[1];
  const float* Wp = (const float*)d_in[2];
  const float* bp = (const float*)d_in[3];
  const float* Wl = (const float*)d_in[4];
  const float* bl = (const float*)d_in[5];
  const float* Wr = (const float*)d_in[6];
  const float* gamma = (const float*)d_in[7];
  const float* beta = (const float*)d_in[8];
  const float* W1 = (const float*)d_in[9];
  const float* b1 = (const float*)d_in[10];
  const float* W2 = (const float*)d_in[11];
  const float* b2 = (const float*)d_in[12];
  float* y = (float*)d_out;

  const int N = in_sizes[0] / FIN;
  const int E = in_sizes[1] / 2;

  // workspace carve (256B aligned chunks)
  char* w = (char*)d_ws;
  auto carve = [&](size_t bytes) -> char* {
    char* p = w;
    w += (bytes + 255) / 256 * 256;
    return p;
  };
  int* deg = (int*)carve((size_t)N * 4);
  int* offsets = (int*)carve(((size_t)N + 1) * 4);
  int* partials = (int*)carve(1024 * 4);
  int* flag = (int*)carve(4);
  float* invdeg = (float*)carve((size_t)N * 4);
  int* csr = (int*)carve((size_t)E * 4);
  float* hA = (float*)carve((size_t)N * HH * 4);
  float* hB = (float*)carve((size_t)N * HH * 4);
  __half* h16A = (__half*)carve((size_t)N * HH * 2);
  __half* h16B = (__half*)carve((size_t)N * HH * 2);
  __half* agg16 = (__half*)carve((size_t)N * HH * 2);  // reused both layers
  int* cursor = deg;  // alias: deg dead after k_scan3 (read-before-write there)

  const int numTiles = (N + STILE - 1) / STILE;
  const int edgeBlocks = (E + 255) / 256;

  k_detect<<<1, 64, 0, stream>>>((const unsigned int*)ei, E, flag);
  hipMemsetAsync(deg, 0, (size_t)N * 4, stream);
  k_hist<<<edgeBlocks, 256, 0, stream>>>(ei, E, flag, deg);
  k_scan1<<<numTiles, STILE, 0, stream>>>(deg, N, partials);
  k_scan2<<<1, 1024, 0, stream>>>(partials, numTiles);
  k_scan3<<<numTiles, STILE, 0, stream>>>(deg, N, partials, offsets, cursor, invdeg);
  k_fill<<<edgeBlocks, 256, 0, stream>>>(ei, E, flag, cursor, csr);
  k_inproj<<<1024, 256, 0, stream>>>(x, Wp, bp, hA, h16A, N);
  // layer 0
  k_gather<<<2048, 256, 0, stream>>>(h16A, offsets, csr, invdeg, agg16, N);
  k_gemv<<<1024, 256, 0, stream>>>(hA, agg16, hB, h16B,
                                   Wl, bl, Wr, gamma, beta, N);
  // layer 1
  k_gather<<<2048, 256, 0, stream>>>(h16B, offsets, csr, invdeg, agg16, N);
  k_gemv<<<1024, 256, 0, stream>>>(hB, agg16, hA, h16A,
                                   Wl + HH * HH, bl + HH, Wr + HH * HH,
                                   gamma + HH, beta + HH, N);
  k_mlp<<<512, 256, 0, stream>>>(hA, W1, b1, W2, b2, y, N);
}

// Round 8
// 509.602 us; speedup vs baseline: 1.0567x; 1.0567x over previous
//
#include <hip/hip_runtime.h>
#include <hip/hip_fp16.h>

#define FIN 16
#define HH 64
#define STILE 256
#define BKT_SHIFT 9          // 512 nodes per bucket
#define MAXBUCK 256          // supports N up to 131072
#define NBLK 128             // bincount/binwrite blocks (must match)

static constexpr float LN_EPS = 1e-5f;

__device__ __forceinline__ float laneval(float v, int l) {
  return __uint_as_float(__builtin_amdgcn_readlane(__float_as_uint(v), l));
}
__device__ __forceinline__ int rfl(int v) { return __builtin_amdgcn_readfirstlane(v); }
__device__ __forceinline__ float rflf(float v) {
  return __uint_as_float(__builtin_amdgcn_readfirstlane(__float_as_uint(v)));
}

// ---- edge dtype detection: int64 edge_index has all-zero high words ----
__global__ void k_detect(const unsigned int* ei, int E, int* flag) {
  int lane = threadIdx.x & 63;
  int n = (E < 64) ? E : 64;
  unsigned int hi = (lane < n) ? ei[2 * lane + 1] : 0u;
  unsigned long long nz = __ballot(hi != 0u);
  if (lane == 0) *flag = (nz == 0ull) ? 1 : 0;
}

// ---- in-degree histogram over dst (for offsets/inv_deg) ----
__global__ void k_hist(const void* ei, int E, const int* __restrict__ flag,
                       int* __restrict__ deg) {
  const int is64 = *flag;
  int e = blockIdx.x * blockDim.x + threadIdx.x;
  if (e >= E) return;
  int d = is64 ? (int)((const long long*)ei)[E + e] : ((const int*)ei)[E + e];
  atomicAdd(&deg[d], 1);
}

// ---- scan level 1: per-tile sums ----
__global__ void k_scan1(const int* __restrict__ deg, int N, int* __restrict__ partials) {
  __shared__ int sm[STILE];
  int t = threadIdx.x, b = blockIdx.x;
  int i = b * STILE + t;
  int v = (i < N) ? deg[i] : 0;
  sm[t] = v;
  __syncthreads();
  for (int off = STILE / 2; off > 0; off >>= 1) {
    if (t < off) sm[t] += sm[t + off];
    __syncthreads();
  }
  if (t == 0) partials[b] = sm[0];
}

// ---- scan level 2: single-block scan of tile sums -> exclusive tile bases ----
__global__ void k_scan2(int* partials, int numTiles) {
  __shared__ int sm[1024];
  int t = threadIdx.x;
  int v = (t < numTiles) ? partials[t] : 0;
  sm[t] = v;
  __syncthreads();
  for (int off = 1; off < 1024; off <<= 1) {
    int x = (t >= off) ? sm[t - off] : 0;
    __syncthreads();
    sm[t] += x;
    __syncthreads();
  }
  if (t < numTiles) partials[t] = sm[t] - v;  // exclusive base
}

// ---- scan level 3: per-element offsets + inv_deg ----
__global__ void k_scan3(const int* __restrict__ deg, int N,
                        const int* __restrict__ partials,
                        int* __restrict__ offsets, float* __restrict__ inv_deg) {
  __shared__ int sm[STILE];
  int t = threadIdx.x, b = blockIdx.x;
  int i = b * STILE + t;
  int v = (i < N) ? deg[i] : 0;
  sm[t] = v;
  __syncthreads();
  for (int off = 1; off < STILE; off <<= 1) {
    int x = (t >= off) ? sm[t - off] : 0;
    __syncthreads();
    sm[t] += x;
    __syncthreads();
  }
  int excl = sm[t] - v + partials[b];
  if (i < N) {
    offsets[i] = excl;
    inv_deg[i] = (v > 0) ? (1.0f / (float)v) : 0.0f;
    if (i == N - 1) offsets[N] = excl + v;
  }
}

// ==== CSR build via multisplit ====
// Round-7 post-mortem: atomic scatter k_fill is WRITE-AMPLIFICATION-bound:
// 1.6M random 4B stores -> ~64B HBM line each (WRITE_SIZE 107MB for a 6.4MB
// array) because lines are shared across XCDs and never merge. Fix = write
// locality: bin edges into 512-node buckets with per-(block,bucket) private
// slices (single-writer lines), then scatter within each bucket's contiguous
// ~32KB csr region from ONE block.

// pass 0: count matrix C[bucket][block]
__global__ __launch_bounds__(256) void k_bincount(const void* ei, int E,
                                                  const int* __restrict__ flag,
                                                  int* __restrict__ Cmat, int nbuck) {
  __shared__ int lh[MAXBUCK];
  const int is64 = *flag;
  int t = threadIdx.x, j = blockIdx.x;
  for (int b = t; b < nbuck; b += 256) lh[b] = 0;
  __syncthreads();
  int chunk = (E + gridDim.x - 1) / gridDim.x;
  int e0 = j * chunk, e1 = (e0 + chunk < E) ? (e0 + chunk) : E;
  for (int e = e0 + t; e < e1; e += 256) {
    int d = is64 ? (int)((const long long*)ei)[E + e] : ((const int*)ei)[E + e];
    atomicAdd(&lh[d >> BKT_SHIFT], 1);
  }
  __syncthreads();
  for (int b = t; b < nbuck; b += 256) Cmat[b * gridDim.x + j] = lh[b];
}

// exclusive scan of Cmat (bucket-major). Bucket-major cumulative == csr base
// of each bucket, so scanned values ARE absolute ebuf cursors.
__global__ void k_scanC(int* __restrict__ C, int len) {
  __shared__ int sm[1024];
  __shared__ int carry;
  int t = threadIdx.x;
  if (t == 0) carry = 0;
  __syncthreads();
  for (int base = 0; base < len; base += 1024) {
    int i = base + t;
    int v = (i < len) ? C[i] : 0;
    sm[t] = v;
    __syncthreads();
    for (int off = 1; off < 1024; off <<= 1) {
      int x = (t >= off) ? sm[t - off] : 0;
      __syncthreads();
      sm[t] += x;
      __syncthreads();
    }
    if (i < len) C[i] = carry + sm[t] - v;  // exclusive
    __syncthreads();
    if (t == 0) carry += sm[1023];
    __syncthreads();
  }
}

// pass 1: write (d,s) packed into ebuf at private per-(block,bucket) cursors
__global__ __launch_bounds__(256) void k_binwrite(const void* ei, int E,
                                                  const int* __restrict__ flag,
                                                  const int* __restrict__ Cmat,
                                                  unsigned long long* __restrict__ ebuf,
                                                  int nbuck) {
  __shared__ int lcur[MAXBUCK];
  const int is64 = *flag;
  int t = threadIdx.x, j = blockIdx.x;
  for (int b = t; b < nbuck; b += 256) lcur[b] = Cmat[b * gridDim.x + j];
  __syncthreads();
  int chunk = (E + gridDim.x - 1) / gridDim.x;
  int e0 = j * chunk, e1 = (e0 + chunk < E) ? (e0 + chunk) : E;
  for (int e = e0 + t; e < e1; e += 256) {
    int s, d;
    if (is64) {
      const long long* p = (const long long*)ei;
      s = (int)p[e];
      d = (int)p[E + e];
    } else {
      const int* p = (const int*)ei;
      s = p[e];
      d = p[E + e];
    }
    int pos = atomicAdd(&lcur[d >> BKT_SHIFT], 1);
    ebuf[pos] = ((unsigned long long)(unsigned)d << 32) | (unsigned)s;
  }
}

// pass 2: one block per bucket; scatter into the bucket's contiguous csr
// range via LDS per-node cursors (single-CU write locality).
__global__ __launch_bounds__(256) void k_binscatter(
    const unsigned long long* __restrict__ ebuf, const int* __restrict__ offsets,
    int N, int* __restrict__ csr) {
  __shared__ int lcur[1 << BKT_SHIFT];
  int b = blockIdx.x, t = threadIdx.x;
  int n0 = b << BKT_SHIFT;
  int n1 = n0 + (1 << BKT_SHIFT);
  if (n1 > N) n1 = N;
  int nn = n1 - n0;
  for (int i = t; i < nn; i += 256) lcur[i] = offsets[n0 + i];
  __syncthreads();
  int p0 = offsets[n0], p1 = offsets[n1];
  for (int p = p0 + t; p < p1; p += 256) {
    unsigned long long pk = ebuf[p];
    int d = (int)(pk >> 32);
    int s = (int)(pk & 0xffffffffull);
    int pos = atomicAdd(&lcur[d - n0], 1);
    csr[pos] = s;
  }
}

// ---- input projection: h = relu(x @ Wp^T + bp), one wave per node ----
__global__ __launch_bounds__(256) void k_inproj(const float* __restrict__ x,
                                                const float* __restrict__ Wp,
                                                const float* __restrict__ bp,
                                                float* __restrict__ h,
                                                __half* __restrict__ h16, int N) {
  int lane = threadIdx.x & 63;
  int wid = (blockIdx.x * blockDim.x + threadIdx.x) >> 6;
  int nwaves = (gridDim.x * blockDim.x) >> 6;
  float w[FIN];
#pragma unroll
  for (int k = 0; k < FIN; ++k) w[k] = Wp[lane * FIN + k];
  float b = bp[lane];
  for (int n = wid; n < N; n += nwaves) {
    const float4* xr = (const float4*)(x + (size_t)n * FIN);
    float a0 = b, a1 = 0.f;
#pragma unroll
    for (int q = 0; q < FIN / 4; ++q) {
      float4 xv = xr[q];
      a0 = fmaf(xv.x, w[4 * q + 0], a0);
      a1 = fmaf(xv.y, w[4 * q + 1], a1);
      a0 = fmaf(xv.z, w[4 * q + 2], a0);
      a1 = fmaf(xv.w, w[4 * q + 3], a1);
    }
    float r = fmaxf(a0 + a1, 0.0f);
    h[(size_t)n * HH + lane] = r;
    h16[(size_t)n * HH + lane] = __float2half(r);
  }
}

// ---- neighbor-mean gather ONLY: agg16[n] = mean of h16 rows ----
__global__ __launch_bounds__(256, 8) void k_gather(
    const __half* __restrict__ h16_in, const int* __restrict__ offsets,
    const int* __restrict__ csr, const float* __restrict__ inv_deg,
    __half* __restrict__ agg16, int N) {
  int lane = threadIdx.x & 63;
  int wid = (blockIdx.x * blockDim.x + threadIdx.x) >> 6;
  int nwaves = (gridDim.x * blockDim.x) >> 6;
  for (int n = wid; n < N; n += nwaves) {
    int p0 = rfl(offsets[n]);
    int p1 = rfl(offsets[n + 1]);
    float idg = rflf(inv_deg[n]);
    float a0 = 0.f, a1 = 0.f, a2 = 0.f, a3 = 0.f;
    int p = p0;
    for (; p + 16 <= p1; p += 16) {
      float v[16];
#pragma unroll
      for (int i = 0; i < 16; ++i) {
        int s = rfl(csr[p + i]);
        v[i] = __half2float(h16_in[(size_t)s * HH + lane]);
      }
      a0 += (v[0] + v[1]) + (v[2] + v[3]);
      a1 += (v[4] + v[5]) + (v[6] + v[7]);
      a2 += (v[8] + v[9]) + (v[10] + v[11]);
      a3 += (v[12] + v[13]) + (v[14] + v[15]);
    }
    for (; p + 4 <= p1; p += 4) {
      int s0 = rfl(csr[p + 0]), s1 = rfl(csr[p + 1]);
      int s2 = rfl(csr[p + 2]), s3 = rfl(csr[p + 3]);
      float v0 = __half2float(h16_in[(size_t)s0 * HH + lane]);
      float v1 = __half2float(h16_in[(size_t)s1 * HH + lane]);
      float v2 = __half2float(h16_in[(size_t)s2 * HH + lane]);
      float v3 = __half2float(h16_in[(size_t)s3 * HH + lane]);
      a0 += (v0 + v1) + (v2 + v3);
    }
    for (; p < p1; ++p) {
      int s = rfl(csr[p]);
      a0 += __half2float(h16_in[(size_t)s * HH + lane]);
    }
    agg16[(size_t)n * HH + lane] = __float2half(((a0 + a1) + (a2 + a3)) * idg);
  }
}

// ---- GEMV x2 + LayerNorm + relu + residual, 2 nodes per wave ----
__global__ __launch_bounds__(256) void k_gemv(
    const float* __restrict__ h_in, const __half* __restrict__ agg16,
    float* __restrict__ h_out, __half* __restrict__ h16_out,
    const float* __restrict__ Wl, const float* __restrict__ bl,
    const float* __restrict__ Wr, const float* __restrict__ gamma,
    const float* __restrict__ beta, int N) {
  int lane = threadIdx.x & 63;
  int wid = (blockIdx.x * blockDim.x + threadIdx.x) >> 6;
  int nwaves = (gridDim.x * blockDim.x) >> 6;
  float blv = bl[lane], g = gamma[lane], be = beta[lane];
  const float4* wlr = (const float4*)(Wl + lane * HH);
  const float4* wrr = (const float4*)(Wr + lane * HH);

  for (int n = 2 * wid; n < N; n += 2 * nwaves) {
    int m2 = (n + 1 < N) ? (n + 1) : n;  // tail duplicates own node (benign)
    float hnA = h_in[(size_t)n * HH + lane];
    float hnB = h_in[(size_t)m2 * HH + lane];
    float acA = __half2float(agg16[(size_t)n * HH + lane]);
    float acB = __half2float(agg16[(size_t)m2 * HH + lane]);

    float olA = blv, orA = 0.f, olB = blv, orB = 0.f;
#pragma unroll
    for (int q = 0; q < HH / 4; ++q) {
      float4 wl4 = wlr[q];
      float4 wr4 = wrr[q];
      olA = fmaf(laneval(acA, 4 * q + 0), wl4.x, olA);
      olB = fmaf(laneval(acB, 4 * q + 0), wl4.x, olB);
      orA = fmaf(laneval(hnA, 4 * q + 0), wr4.x, orA);
      orB = fmaf(laneval(hnB, 4 * q + 0), wr4.x, orB);
      olA = fmaf(laneval(acA, 4 * q + 1), wl4.y, olA);
      olB = fmaf(laneval(acB, 4 * q + 1), wl4.y, olB);
      orA = fmaf(laneval(hnA, 4 * q + 1), wr4.y, orA);
      orB = fmaf(laneval(hnB, 4 * q + 1), wr4.y, orB);
      olA = fmaf(laneval(acA, 4 * q + 2), wl4.z, olA);
      olB = fmaf(laneval(acB, 4 * q + 2), wl4.z, olB);
      orA = fmaf(laneval(hnA, 4 * q + 2), wr4.z, orA);
      orB = fmaf(laneval(hnB, 4 * q + 2), wr4.z, orB);
      olA = fmaf(laneval(acA, 4 * q + 3), wl4.w, olA);
      olB = fmaf(laneval(acB, 4 * q + 3), wl4.w, olB);
      orA = fmaf(laneval(hnA, 4 * q + 3), wr4.w, orA);
      orB = fmaf(laneval(hnB, 4 * q + 3), wr4.w, orB);
    }

#pragma unroll
    for (int b = 0; b < 2; ++b) {
      float out = (b == 0) ? (olA + orA) : (olB + orB);
      float hn = (b == 0) ? hnA : hnB;
      int m = (b == 0) ? n : m2;
      float s = out;
#pragma unroll
      for (int msk = 1; msk < 64; msk <<= 1) s += __shfl_xor(s, msk);
      float mu = s * (1.0f / 64.0f);
      float d = out - mu;
      float vs = d * d;
#pragma unroll
      for (int msk = 1; msk < 64; msk <<= 1) vs += __shfl_xor(vs, msk);
      float var = vs * (1.0f / 64.0f);
      float val = fmaf(d * rsqrtf(var + LN_EPS), g, be);
      float res = fmaxf(val, 0.0f) + hn;
      h_out[(size_t)m * HH + lane] = res;
      h16_out[(size_t)m * HH + lane] = __float2half(res);
    }
  }
}

// ---- MLP head: y = relu(h@W1^T + b1) @ W2^T + b2 ; 2 nodes per wave ----
__global__ __launch_bounds__(256) void k_mlp(const float* __restrict__ h,
                                             const float* __restrict__ W1,
                                             const float* __restrict__ b1,
                                             const float* __restrict__ W2,
                                             const float* __restrict__ b2,
                                             float* __restrict__ y, int N) {
  int lane = threadIdx.x & 63;
  int half = lane >> 5;
  int j = lane & 31;
  int wid = (blockIdx.x * blockDim.x + threadIdx.x) >> 6;
  int nwaves = (gridDim.x * blockDim.x) >> 6;

  float w1[HH];
#pragma unroll
  for (int k = 0; k < HH; ++k) w1[k] = W1[j * HH + k];
  float b1v = b1[j], w2v = W2[j], b2v = b2[0];

  for (int base = wid * 2; base < N; base += nwaves * 2) {
    int n = base + half;
    float t0 = b1v, t1 = 0.0f;
    if (n < N) {
      const float4* hr = (const float4*)(h + (size_t)n * HH);
#pragma unroll
      for (int q = 0; q < HH / 4; ++q) {
        float4 hv = hr[q];
        t0 = fmaf(hv.x, w1[4 * q + 0], t0);
        t1 = fmaf(hv.y, w1[4 * q + 1], t1);
        t0 = fmaf(hv.z, w1[4 * q + 2], t0);
        t1 = fmaf(hv.w, w1[4 * q + 3], t1);
      }
    }
    float t = fmaxf(t0 + t1, 0.0f) * w2v;
#pragma unroll
    for (int m = 1; m < 32; m <<= 1) t += __shfl_xor(t, m);  // stays in half
    if (j == 0 && n < N) y[n] = t + b2v;
  }
}

extern "C" void kernel_launch(void* const* d_in, const int* in_sizes, int n_in,
                              void* d_out, int out_size, void* d_ws, size_t ws_size,
                              hipStream_t stream) {
  const float* x = (const float*)d_in[0];
  const void* ei = d_in[1];
  const float* Wp = (const float*)d_in[2];
  const float* bp = (const float*)d_in[3];
  const float* Wl = (const float*)d_in[4];
  const float* bl = (const float*)d_in[5];
  const float* Wr = (const float*)d_in[6];
  const float* gamma = (const float*)d_in[7];
  const float* beta = (const float*)d_in[8];
  const float* W1 = (const float*)d_in[9];
  const float* b1 = (const float*)d_in[10];
  const float* W2 = (const float*)d_in[11];
  const float* b2 = (const float*)d_in[12];
  float* y = (float*)d_out;

  const int N = in_sizes[0] / FIN;
  const int E = in_sizes[1] / 2;
  const int nbuck = (N + (1 << BKT_SHIFT) - 1) >> BKT_SHIFT;  // <= MAXBUCK

  // workspace carve (256B aligned chunks)
  char* w = (char*)d_ws;
  auto carve = [&](size_t bytes) -> char* {
    char* p = w;
    w += (bytes + 255) / 256 * 256;
    return p;
  };
  int* deg = (int*)carve((size_t)N * 4);
  int* offsets = (int*)carve(((size_t)N + 1) * 4);
  int* partials = (int*)carve(1024 * 4);
  int* flag = (int*)carve(4);
  float* invdeg = (float*)carve((size_t)N * 4);
  int* csr = (int*)carve((size_t)E * 4);
  int* Cmat = (int*)carve((size_t)MAXBUCK * NBLK * 4);
  unsigned long long* ebuf = (unsigned long long*)carve((size_t)E * 8);
  float* hA = (float*)carve((size_t)N * HH * 4);
  float* hB = (float*)carve((size_t)N * HH * 4);
  __half* h16A = (__half*)carve((size_t)N * HH * 2);
  __half* h16B = (__half*)carve((size_t)N * HH * 2);
  __half* agg16 = (__half*)carve((size_t)N * HH * 2);  // reused both layers

  const int numTiles = (N + STILE - 1) / STILE;
  const int edgeBlocks = (E + 255) / 256;

  k_detect<<<1, 64, 0, stream>>>((const unsigned int*)ei, E, flag);
  hipMemsetAsync(deg, 0, (size_t)N * 4, stream);
  k_hist<<<edgeBlocks, 256, 0, stream>>>(ei, E, flag, deg);
  k_scan1<<<numTiles, STILE, 0, stream>>>(deg, N, partials);
  k_scan2<<<1, 1024, 0, stream>>>(partials, numTiles);
  k_scan3<<<numTiles, STILE, 0, stream>>>(deg, N, partials, offsets, invdeg);
  // CSR build: multisplit (write-local, no global atomics)
  k_bincount<<<NBLK, 256, 0, stream>>>(ei, E, flag, Cmat, nbuck);
  k_scanC<<<1, 1024, 0, stream>>>(Cmat, nbuck * NBLK);
  k_binwrite<<<NBLK, 256, 0, stream>>>(ei, E, flag, Cmat, ebuf, nbuck);
  k_binscatter<<<nbuck, 256, 0, stream>>>(ebuf, offsets, N, csr);
  k_inproj<<<1024, 256, 0, stream>>>(x, Wp, bp, hA, h16A, N);
  // layer 0
  k_gather<<<2048, 256, 0, stream>>>(h16A, offsets, csr, invdeg, agg16, N);
  k_gemv<<<1024, 256, 0, stream>>>(hA, agg16, hB, h16B,
                                   Wl, bl, Wr, gamma, beta, N);
  // layer 1
  k_gather<<<2048, 256, 0, stream>>>(h16B, offsets, csr, invdeg, agg16, N);
  k_gemv<<<1024, 256, 0, stream>>>(hB, agg16, hA, h16A,
                                   Wl + HH * HH, bl + HH, Wr + HH * HH,
                                   gamma + HH, beta + HH, N);
  k_mlp<<<512, 256, 0, stream>>>(hA, W1, b1, W2, b2, y, N);
}